// Round 11
// baseline (1448.094 us; speedup 1.0000x reference)
//
#include <hip/hip_runtime.h>

// GRU: T=512, B=256, I=H=256, fp32 in/out.
// Stage A (parallel GEMM): Gx = x @ Wx_cat^T + b, bf16 in d_ws.
//   Layout: gx[tile = t*16+bg][colblk 0..191][batch 0..15][colin 0..3], bf16.
// Stage B (recurrent): 16 WGs x 1024 thr (16 waves = 4/SIMD); 16 batch rows/WG;
//   weights persistent in registers as MFMA A-fragments (D = W*h^T), 96
//   regs/lane (w1[2][8] z-or-r 32 cols + w2[8] 16 cand cols). gx read directly
//   into accumulator-init VGPRs, prefetched one step ahead; raw lgkmcnt-only
//   barriers (no vmcnt drain in loop); frag-ordered hA/rhA (0-conflict
//   ds_read_b128); h_s/zt_s padded to 268.
// r11 rationale: at 8 waves (2/SIMD) MfmaUtil+VALUBusy were additive (76% of
//   active-CU cycles) = intra-wave cluster serialization; 4 waves/SIMD lets
//   the scheduler overlap one wave's MFMA cluster with another's VALU/trans.
// Rule #20: all register arrays indexed by compile-time constants only.

typedef float f32x4 __attribute__((ext_vector_type(4)));
typedef short bf16x8 __attribute__((ext_vector_type(8)));

__device__ __forceinline__ unsigned short f2bf(float f) {
  union { float f; unsigned int u; } v; v.f = f;
  unsigned int u = v.u + 0x7fffu + ((v.u >> 16) & 1u);   // RNE
  return (unsigned short)(u >> 16);
}
__device__ __forceinline__ float u2f(unsigned int u) {
  union { unsigned int u; float f; } v; v.u = u; return v.f;
}
__device__ __forceinline__ unsigned int cvt_pk_bf16(float lo, float hi) {
  unsigned int r;
  asm("v_cvt_pk_bf16_f32 %0, %1, %2" : "=v"(r) : "v"(lo), "v"(hi));
  return r;
}
__device__ __forceinline__ float sigmoid_f(float x) {
  return __builtin_amdgcn_rcpf(1.f + __expf(-x));
}
__device__ __forceinline__ float tanh_f(float x) {
  float e = __expf(2.f * x);
  return 1.f - 2.f * __builtin_amdgcn_rcpf(e + 1.f);
}
__device__ __forceinline__ f32x4 unpk(uint2 gv) {
  f32x4 a;
  a[0] = u2f(gv.x << 16); a[1] = u2f(gv.x & 0xffff0000u);
  a[2] = u2f(gv.y << 16); a[3] = u2f(gv.y & 0xffff0000u);
  return a;
}
// col j (0..255), batch b -> short offset in fragment-ordered [kk][lg][16][8]
__device__ __forceinline__ int frag_off(int j, int b) {
  return ((j >> 5) * 64 + ((j >> 3) & 3) * 16 + b) * 8 + (j & 7);
}

// ---------------- Stage A ----------------
// grid (2048, 12), block 256 (4 waves). Tile 64M x 64N, K=256 in 4 chunks.
__global__ __launch_bounds__(256) void gru_gx_kernel(
    const float* __restrict__ x,
    const float* __restrict__ Wz, const float* __restrict__ Wr, const float* __restrict__ Wc,
    const float* __restrict__ bz, const float* __restrict__ br, const float* __restrict__ bc,
    unsigned short* __restrict__ gx)
{
  __shared__ __align__(16) unsigned short As[64][72];  // [m][k] bf16, +8 pad
  __shared__ __align__(16) unsigned short Bs[64][72];  // [j][k] bf16

  const int tid  = threadIdx.x;
  const int lane = tid & 63;
  const int wid  = tid >> 6;       // 0..3
  const int l15  = lane & 15;
  const int lg   = lane >> 4;      // 0..3
  const int m0   = blockIdx.x * 64;      // m = t*256 + b
  const int by   = blockIdx.y;           // 0..11
  const int gate = by >> 2;
  const int jb   = (by & 3) * 64;
  const float* W    = (gate == 0) ? Wz : ((gate == 1) ? Wr : Wc);
  const float* bias = (gate == 0) ? bz : ((gate == 1) ? br : bc);

  f32x4 acc[4];
  #pragma unroll
  for (int n = 0; n < 4; ++n) acc[n] = (f32x4){0.f, 0.f, 0.f, 0.f};

  for (int k0 = 0; k0 < 256; k0 += 64) {
    #pragma unroll
    for (int i = 0; i < 4; ++i) {
      int idx = tid + i * 256;              // 0..1023
      int row = idx >> 4;                   // 0..63
      int kq  = (idx & 15) << 2;            // 0..60 step 4
      float4 va = *(const float4*)(x + (size_t)(m0 + row) * 256 + k0 + kq);
      ushort4 ua; ua.x = f2bf(va.x); ua.y = f2bf(va.y); ua.z = f2bf(va.z); ua.w = f2bf(va.w);
      *(ushort4*)&As[row][kq] = ua;
      float4 vb = *(const float4*)(W + (size_t)(jb + row) * 512 + 256 + k0 + kq);
      ushort4 ub; ub.x = f2bf(vb.x); ub.y = f2bf(vb.y); ub.z = f2bf(vb.z); ub.w = f2bf(vb.w);
      *(ushort4*)&Bs[row][kq] = ub;
    }
    __syncthreads();
    #pragma unroll
    for (int ks = 0; ks < 64; ks += 32) {
      bf16x8 af = *(const bf16x8*)&As[wid * 16 + l15][ks + lg * 8];
      #pragma unroll
      for (int n = 0; n < 4; ++n) {
        bf16x8 bf = *(const bf16x8*)&Bs[n * 16 + l15][ks + lg * 8];
        acc[n] = __builtin_amdgcn_mfma_f32_16x16x32_bf16(af, bf, acc[n], 0, 0, 0);
      }
    }
    __syncthreads();
  }

  // bias + bf16; transpose staging: Ts[m 64][j 64] (reuse As, stride 72)
  #pragma unroll
  for (int n = 0; n < 4; ++n) {
    float bv = bias[jb + n * 16 + l15];
    #pragma unroll
    for (int r = 0; r < 4; ++r) {
      As[wid * 16 + lg * 4 + r][n * 16 + l15] = f2bf(acc[n][r] + bv);
    }
  }
  __syncthreads();

  const int tt    = m0 >> 8;       // t (tile spans a single t since 64 | 256)
  const int b0    = m0 & 255;      // batch base, 64-aligned
  const int jbase = by * 64;       // global output col base
  #pragma unroll
  for (int i = 0; i < 2; ++i) {
    int u    = tid + i * 256;      // 0..511
    int bg_l = u >> 7;             // 0..3 (16-batch group within tile's 64 batches)
    int rem  = u & 127;
    int cb_l = rem >> 3;           // 0..15 colblk within the 64-col slice
    int bp   = rem & 7;            // batch pair
    int row0 = bg_l * 16 + bp * 2;
    uint2 lo = *(const uint2*)&As[row0][cb_l * 4];
    uint2 hi = *(const uint2*)&As[row0 + 1][cb_l * 4];
    uint4 val; val.x = lo.x; val.y = lo.y; val.z = hi.x; val.w = hi.y;
    size_t off = (((size_t)tt * 16 + (b0 >> 4) + bg_l) * 192 + (jbase >> 2) + cb_l) * 64
                 + (size_t)bp * 8;   // shorts
    *(uint4*)(gx + off) = val;
  }
}

// ---------------- Stage B ----------------
// grid 16, block 1024 (16 waves, 4/SIMD). WG wg owns batch rows [16wg,16wg+16).
// Phase 1: waves 0-7 -> z cols (w*32), waves 8-15 -> r cols ((w-8)*32).
// Phase 2: all 16 waves -> cand, 16 cols each (wid*16).
__global__ __launch_bounds__(1024, 1) void gru_rec_kernel(
    const unsigned short* __restrict__ gx,
    const float* __restrict__ h0,
    const float* __restrict__ Wz, const float* __restrict__ Wr, const float* __restrict__ Wc,
    float* __restrict__ out)
{
  __shared__ __align__(16) float h_s[16][268];           // [batch][col] f32, pad 268
  __shared__ __align__(16) float zt_s[16][268];          // [batch][col] f32, pad 268
  __shared__ __align__(16) unsigned short hA[4096];      // bf16 h, frag-ordered
  __shared__ __align__(16) unsigned short rhA[4096];     // bf16 r*h, frag-ordered

  const int tid   = threadIdx.x;
  const int lane  = tid & 63;
  const int wid   = tid >> 6;       // 0..15
  const int w7    = wid & 7;
  const int zr    = wid >> 3;       // 0 = z-duty, 1 = r-duty (phase 1)
  const int l15   = lane & 15;
  const int lg    = lane >> 4;      // 0..3
  const int wg    = blockIdx.x;
  const int brow0 = wg * 16;

  // ---- persistent weights: bf16 MFMA A-fragments ----
  bf16x8 w1[2][8];   // phase-1: 32 cols (z for zr=0, r for zr=1), K=256 -> 64 regs
  {
    const float* W  = zr ? Wr : Wz;
    const int    cb = w7 * 32;
    #pragma unroll
    for (int n = 0; n < 2; ++n) {
      const int j = cb + n * 16 + l15;
      #pragma unroll
      for (int kk = 0; kk < 8; ++kk) {
        const int k = kk * 32 + lg * 8;
        const float* p = W + (size_t)j * 512 + k;      // h-part: cols [0,256)
        float4 a = *(const float4*)p;
        float4 b = *(const float4*)(p + 4);
        bf16x8 f;
        f[0] = (short)f2bf(a.x); f[1] = (short)f2bf(a.y);
        f[2] = (short)f2bf(a.z); f[3] = (short)f2bf(a.w);
        f[4] = (short)f2bf(b.x); f[5] = (short)f2bf(b.y);
        f[6] = (short)f2bf(b.z); f[7] = (short)f2bf(b.w);
        w1[n][kk] = f;
      }
    }
  }
  bf16x8 w2[8];      // phase-2: 16 cand cols, K=256 -> 32 regs
  {
    const int j = wid * 16 + l15;
    #pragma unroll
    for (int kk = 0; kk < 8; ++kk) {
      const int k = kk * 32 + lg * 8;
      const float* p = Wc + (size_t)j * 512 + k;
      float4 a = *(const float4*)p;
      float4 b = *(const float4*)(p + 4);
      bf16x8 f;
      f[0] = (short)f2bf(a.x); f[1] = (short)f2bf(a.y);
      f[2] = (short)f2bf(a.z); f[3] = (short)f2bf(a.w);
      f[4] = (short)f2bf(b.x); f[5] = (short)f2bf(b.y);
      f[6] = (short)f2bf(b.z); f[7] = (short)f2bf(b.w);
      w2[kk] = f;
    }
  }

  // ---- init h ----
  for (int idx = tid; idx < 16 * 256; idx += 1024) {
    int r = idx >> 8, c = idx & 255;
    float v = h0[(size_t)(brow0 + r) * 256 + c];
    h_s[r][c] = v;
    hA[frag_off(c, r)] = f2bf(v);
  }

  // ---- prefetch t=0 gx into registers ----
  // phase-1 colblk: zr*64 + w7*8 + n*4 + lg ; phase-2 colblk: 128 + wid*4 + lg
  uint2 g1[2], g2;
  {
    const size_t tb = (size_t)wg * 12288;
    #pragma unroll
    for (int n = 0; n < 2; ++n)
      g1[n] = *(const uint2*)(gx + tb + (size_t)(zr * 64 + w7 * 8 + n * 4 + lg) * 64 + l15 * 4);
    g2 = *(const uint2*)(gx + tb + (size_t)(128 + wid * 4 + lg) * 64 + l15 * 4);
  }
  __syncthreads();   // h_s/hA visible

  for (int t = 0; t < 512; ++t) {
    const int tn = (t < 511) ? (t + 1) : 511;
    const size_t tbn = ((size_t)tn * 16 + wg) * 12288;

    // ---------- phase 1: z,r ----------
    f32x4 acc[2];
    #pragma unroll
    for (int n = 0; n < 2; ++n) acc[n] = unpk(g1[n]);
    // issue next-step phase-1 prefetch (full step to land)
    #pragma unroll
    for (int n = 0; n < 2; ++n)
      g1[n] = *(const uint2*)(gx + tbn + (size_t)(zr * 64 + w7 * 8 + n * 4 + lg) * 64 + l15 * 4);

    #pragma unroll
    for (int kk = 0; kk < 8; ++kk) {   // compile-time kk (rule #20)
      bf16x8 hf = *(const bf16x8*)&hA[kk * 512 + lane * 8];   // linear, 0-conflict
      #pragma unroll
      for (int n = 0; n < 2; ++n)      // SWAPPED: weights as A, h^T as B
        acc[n] = __builtin_amdgcn_mfma_f32_16x16x32_bf16(w1[n][kk], hf, acc[n], 0, 0, 0);
    }
    if (zr == 0) {         // z gate: zt_s[batch=l15][4 consecutive cols]
      #pragma unroll
      for (int n = 0; n < 2; ++n) {
        const int c0 = w7 * 32 + n * 16 + lg * 4;
        f32x4 zv;
        #pragma unroll
        for (int r = 0; r < 4; ++r) zv[r] = sigmoid_f(acc[n][r]);
        *(f32x4*)&zt_s[l15][c0] = zv;
      }
    } else {               // r gate -> rh = r*h, bf16 pairs (frag-ordered)
      #pragma unroll
      for (int n = 0; n < 2; ++n) {
        const int c0h = w7 * 32 + n * 16 + lg * 4;   // hidden col 0..255
        f32x4 hv = *(const f32x4*)&h_s[l15][c0h];
        float rh0 = sigmoid_f(acc[n][0]) * hv[0];
        float rh1 = sigmoid_f(acc[n][1]) * hv[1];
        float rh2 = sigmoid_f(acc[n][2]) * hv[2];
        float rh3 = sigmoid_f(acc[n][3]) * hv[3];
        uint2 pk; pk.x = cvt_pk_bf16(rh0, rh1); pk.y = cvt_pk_bf16(rh2, rh3);
        *(uint2*)&rhA[frag_off(c0h, l15)] = pk;
      }
    }
    // raw barrier: LDS ordering only, never drain vmcnt in the loop
    asm volatile("s_waitcnt lgkmcnt(0)" ::: "memory");
    __builtin_amdgcn_s_barrier();
    __builtin_amdgcn_sched_barrier(0);

    // ---------- phase 2: cand + h update ----------
    f32x4 acc2 = unpk(g2);
    g2 = *(const uint2*)(gx + tbn + (size_t)(128 + wid * 4 + lg) * 64 + l15 * 4);

    #pragma unroll
    for (int kk = 0; kk < 8; ++kk) {   // compile-time kk
      bf16x8 rf = *(const bf16x8*)&rhA[kk * 512 + lane * 8];  // linear, 0-conflict
      acc2 = __builtin_amdgcn_mfma_f32_16x16x32_bf16(w2[kk], rf, acc2, 0, 0, 0);
    }
    {
      const int j0 = wid * 16 + lg * 4;
      f32x4 zv = *(const f32x4*)&zt_s[l15][j0];
      f32x4 hp = *(const f32x4*)&h_s[l15][j0];
      f32x4 ht;
      #pragma unroll
      for (int r = 0; r < 4; ++r) {
        float th = tanh_f(acc2[r]);
        ht[r] = hp[r] + zv[r] * (th - hp[r]);
      }
      *(f32x4*)(out + (size_t)t * 65536 + (size_t)(brow0 + l15) * 256 + j0) = ht;
      if (t == 511)
        *(f32x4*)(out + (size_t)33554432 + (size_t)(brow0 + l15) * 256 + j0) = ht;
      *(f32x4*)&h_s[l15][j0] = ht;
      uint2 pk; pk.x = cvt_pk_bf16(ht[0], ht[1]); pk.y = cvt_pk_bf16(ht[2], ht[3]);
      *(uint2*)&hA[frag_off(j0, l15)] = pk;
    }
    asm volatile("s_waitcnt lgkmcnt(0)" ::: "memory");
    __builtin_amdgcn_s_barrier();
    __builtin_amdgcn_sched_barrier(0);
  }
}

extern "C" void kernel_launch(void* const* d_in, const int* in_sizes, int n_in,
                              void* d_out, int out_size, void* d_ws, size_t ws_size,
                              hipStream_t stream) {
  const float* x  = (const float*)d_in[0];
  const float* h0 = (const float*)d_in[1];
  const float* Wz = (const float*)d_in[2];
  const float* bz = (const float*)d_in[3];
  const float* Wr = (const float*)d_in[4];
  const float* br = (const float*)d_in[5];
  const float* Wc = (const float*)d_in[6];
  const float* bc = (const float*)d_in[7];
  float* out = (float*)d_out;
  unsigned short* gxbuf = (unsigned short*)d_ws;   // 768*131072*2 = 201.3 MB

  dim3 gridA(2048, 12);
  gru_gx_kernel<<<gridA, 256, 0, stream>>>(x, Wz, Wr, Wc, bz, br, bc, gxbuf);
  gru_rec_kernel<<<16, 1024, 0, stream>>>(gxbuf, h0, Wz, Wr, Wc, out);
}

// Round 12
// 1312.383 us; speedup vs baseline: 1.1034x; 1.1034x over previous
//
#include <hip/hip_runtime.h>

// GRU: T=512, B=256, I=H=256, fp32 in/out.
// Stage A (parallel GEMM): Gx = x @ Wx_cat^T + b, bf16 in d_ws.
//   Layout: gx[tile = t*16+bg][colblk 0..191][batch 0..15][colin 0..3], bf16.
// Stage B (recurrent): 16 WGs x 512 thr (8 waves = 2/SIMD, best measured);
//   16 batch rows/WG; weights persistent in registers as MFMA A-fragments
//   (D = W*h^T). gx read directly into accumulator-init VGPRs, prefetched one
//   step ahead; raw lgkmcnt-only barriers; frag-ordered hA/rhA (0-conflict);
//   h_s/zt_s padded to 268.
// r12: VALU-diet addressing — scalar (uniform) gx/out base pointers advanced
//   by constant strides per step + loop-invariant per-lane offsets (emits
//   saddr+voffset load/store forms); last iteration peeled (no tn clamp, no
//   per-store t==511 branch in hot loop).
// Rule #20: all register arrays indexed by compile-time constants only.

typedef float f32x4 __attribute__((ext_vector_type(4)));
typedef short bf16x8 __attribute__((ext_vector_type(8)));

__device__ __forceinline__ unsigned short f2bf(float f) {
  union { float f; unsigned int u; } v; v.f = f;
  unsigned int u = v.u + 0x7fffu + ((v.u >> 16) & 1u);   // RNE
  return (unsigned short)(u >> 16);
}
__device__ __forceinline__ float u2f(unsigned int u) {
  union { unsigned int u; float f; } v; v.u = u; return v.f;
}
__device__ __forceinline__ unsigned int cvt_pk_bf16(float lo, float hi) {
  unsigned int r;
  asm("v_cvt_pk_bf16_f32 %0, %1, %2" : "=v"(r) : "v"(lo), "v"(hi));
  return r;
}
__device__ __forceinline__ float sigmoid_f(float x) {
  return __builtin_amdgcn_rcpf(1.f + __expf(-x));
}
__device__ __forceinline__ float tanh_f(float x) {
  float e = __expf(2.f * x);
  return 1.f - 2.f * __builtin_amdgcn_rcpf(e + 1.f);
}
__device__ __forceinline__ f32x4 unpk(uint2 gv) {
  f32x4 a;
  a[0] = u2f(gv.x << 16); a[1] = u2f(gv.x & 0xffff0000u);
  a[2] = u2f(gv.y << 16); a[3] = u2f(gv.y & 0xffff0000u);
  return a;
}
// col j (0..255), batch b -> short offset in fragment-ordered [kk][lg][16][8]
__device__ __forceinline__ int frag_off(int j, int b) {
  return ((j >> 5) * 64 + ((j >> 3) & 3) * 16 + b) * 8 + (j & 7);
}

// ---------------- Stage A ----------------
// grid (2048, 12), block 256 (4 waves). Tile 64M x 64N, K=256 in 4 chunks.
__global__ __launch_bounds__(256) void gru_gx_kernel(
    const float* __restrict__ x,
    const float* __restrict__ Wz, const float* __restrict__ Wr, const float* __restrict__ Wc,
    const float* __restrict__ bz, const float* __restrict__ br, const float* __restrict__ bc,
    unsigned short* __restrict__ gx)
{
  __shared__ __align__(16) unsigned short As[64][72];  // [m][k] bf16, +8 pad
  __shared__ __align__(16) unsigned short Bs[64][72];  // [j][k] bf16

  const int tid  = threadIdx.x;
  const int lane = tid & 63;
  const int wid  = tid >> 6;       // 0..3
  const int l15  = lane & 15;
  const int lg   = lane >> 4;      // 0..3
  const int m0   = blockIdx.x * 64;      // m = t*256 + b
  const int by   = blockIdx.y;           // 0..11
  const int gate = by >> 2;
  const int jb   = (by & 3) * 64;
  const float* W    = (gate == 0) ? Wz : ((gate == 1) ? Wr : Wc);
  const float* bias = (gate == 0) ? bz : ((gate == 1) ? br : bc);

  f32x4 acc[4];
  #pragma unroll
  for (int n = 0; n < 4; ++n) acc[n] = (f32x4){0.f, 0.f, 0.f, 0.f};

  for (int k0 = 0; k0 < 256; k0 += 64) {
    #pragma unroll
    for (int i = 0; i < 4; ++i) {
      int idx = tid + i * 256;              // 0..1023
      int row = idx >> 4;                   // 0..63
      int kq  = (idx & 15) << 2;            // 0..60 step 4
      float4 va = *(const float4*)(x + (size_t)(m0 + row) * 256 + k0 + kq);
      ushort4 ua; ua.x = f2bf(va.x); ua.y = f2bf(va.y); ua.z = f2bf(va.z); ua.w = f2bf(va.w);
      *(ushort4*)&As[row][kq] = ua;
      float4 vb = *(const float4*)(W + (size_t)(jb + row) * 512 + 256 + k0 + kq);
      ushort4 ub; ub.x = f2bf(vb.x); ub.y = f2bf(vb.y); ub.z = f2bf(vb.z); ub.w = f2bf(vb.w);
      *(ushort4*)&Bs[row][kq] = ub;
    }
    __syncthreads();
    #pragma unroll
    for (int ks = 0; ks < 64; ks += 32) {
      bf16x8 af = *(const bf16x8*)&As[wid * 16 + l15][ks + lg * 8];
      #pragma unroll
      for (int n = 0; n < 4; ++n) {
        bf16x8 bf = *(const bf16x8*)&Bs[n * 16 + l15][ks + lg * 8];
        acc[n] = __builtin_amdgcn_mfma_f32_16x16x32_bf16(af, bf, acc[n], 0, 0, 0);
      }
    }
    __syncthreads();
  }

  // bias + bf16; transpose staging: Ts[m 64][j 64] (reuse As, stride 72)
  #pragma unroll
  for (int n = 0; n < 4; ++n) {
    float bv = bias[jb + n * 16 + l15];
    #pragma unroll
    for (int r = 0; r < 4; ++r) {
      As[wid * 16 + lg * 4 + r][n * 16 + l15] = f2bf(acc[n][r] + bv);
    }
  }
  __syncthreads();

  const int tt    = m0 >> 8;       // t (tile spans a single t since 64 | 256)
  const int b0    = m0 & 255;      // batch base, 64-aligned
  const int jbase = by * 64;       // global output col base
  #pragma unroll
  for (int i = 0; i < 2; ++i) {
    int u    = tid + i * 256;      // 0..511
    int bg_l = u >> 7;             // 0..3 (16-batch group within tile's 64 batches)
    int rem  = u & 127;
    int cb_l = rem >> 3;           // 0..15 colblk within the 64-col slice
    int bp   = rem & 7;            // batch pair
    int row0 = bg_l * 16 + bp * 2;
    uint2 lo = *(const uint2*)&As[row0][cb_l * 4];
    uint2 hi = *(const uint2*)&As[row0 + 1][cb_l * 4];
    uint4 val; val.x = lo.x; val.y = lo.y; val.z = hi.x; val.w = hi.y;
    size_t off = (((size_t)tt * 16 + (b0 >> 4) + bg_l) * 192 + (jbase >> 2) + cb_l) * 64
                 + (size_t)bp * 8;   // shorts
    *(uint4*)(gx + off) = val;
  }
}

// ---------------- Stage B ----------------
// grid 16, block 512 (8 waves). WG wg owns batch rows [16wg, 16wg+16).
// Phase 1: waves 0-3 -> z cols (wid*64), waves 4-7 -> r cols (wid*64).
// Phase 2: all 8 waves -> cand, 32 cols each (wid*32).
__global__ __launch_bounds__(512, 1) void gru_rec_kernel(
    const unsigned short* __restrict__ gx,
    const float* __restrict__ h0,
    const float* __restrict__ Wz, const float* __restrict__ Wr, const float* __restrict__ Wc,
    float* __restrict__ out)
{
  __shared__ __align__(16) float h_s[16][268];           // [batch][col] f32, pad 268
  __shared__ __align__(16) float zt_s[16][268];          // [batch][col] f32, pad 268
  __shared__ __align__(16) unsigned short hA[4096];      // bf16 h, frag-ordered
  __shared__ __align__(16) unsigned short rhA[4096];     // bf16 r*h, frag-ordered

  const int tid   = threadIdx.x;
  const int lane  = tid & 63;
  const int wid   = tid >> 6;       // 0..7
  const int l15   = lane & 15;
  const int lg    = lane >> 4;      // 0..3
  const int wg    = blockIdx.x;
  const int brow0 = wg * 16;

  // ---- persistent weights: bf16 MFMA A-fragments ----
  bf16x8 w1[4][8];   // phase-1: 64 cols (z for wid<4, r for wid>=4), K=256
  {
    const float* W  = (wid < 4) ? Wz : Wr;
    const int    cb = (wid & 3) * 64;
    #pragma unroll
    for (int n = 0; n < 4; ++n) {
      const int j = cb + n * 16 + l15;
      #pragma unroll
      for (int kk = 0; kk < 8; ++kk) {
        const int k = kk * 32 + lg * 8;
        const float* p = W + (size_t)j * 512 + k;      // h-part: cols [0,256)
        float4 a = *(const float4*)p;
        float4 b = *(const float4*)(p + 4);
        bf16x8 f;
        f[0] = (short)f2bf(a.x); f[1] = (short)f2bf(a.y);
        f[2] = (short)f2bf(a.z); f[3] = (short)f2bf(a.w);
        f[4] = (short)f2bf(b.x); f[5] = (short)f2bf(b.y);
        f[6] = (short)f2bf(b.z); f[7] = (short)f2bf(b.w);
        w1[n][kk] = f;
      }
    }
  }
  bf16x8 w2[2][8];   // phase-2: 32 cand cols, K=256
  {
    const int cb = wid * 32;
    #pragma unroll
    for (int n = 0; n < 2; ++n) {
      const int j = cb + n * 16 + l15;
      #pragma unroll
      for (int kk = 0; kk < 8; ++kk) {
        const int k = kk * 32 + lg * 8;
        const float* p = Wc + (size_t)j * 512 + k;
        float4 a = *(const float4*)p;
        float4 b = *(const float4*)(p + 4);
        bf16x8 f;
        f[0] = (short)f2bf(a.x); f[1] = (short)f2bf(a.y);
        f[2] = (short)f2bf(a.z); f[3] = (short)f2bf(a.w);
        f[4] = (short)f2bf(b.x); f[5] = (short)f2bf(b.y);
        f[6] = (short)f2bf(b.z); f[7] = (short)f2bf(b.w);
        w2[n][kk] = f;
      }
    }
  }

  // ---- init h ----
  for (int idx = tid; idx < 16 * 256; idx += 512) {
    int r = idx >> 8, c = idx & 255;
    float v = h0[(size_t)(brow0 + r) * 256 + c];
    h_s[r][c] = v;
    hA[frag_off(c, r)] = f2bf(v);
  }

  // ---- loop-invariant per-lane offsets (shorts / floats) ----
  int voff1[4], voff2[2], ooff[2];
  #pragma unroll
  for (int n = 0; n < 4; ++n)
    voff1[n] = (wid * 16 + n * 4 + lg) * 64 + l15 * 4;
  #pragma unroll
  for (int n = 0; n < 2; ++n) {
    voff2[n] = (128 + wid * 8 + n * 4 + lg) * 64 + l15 * 4;
    ooff[n]  = l15 * 256 + wid * 32 + n * 16 + lg * 4;
  }
  const int TSTEP = 16 * 12288;                // shorts per t-step

  // uniform (scalar) base pointers
  const unsigned short* gp = gx + (size_t)wg * 12288;    // tile for t=0
  float* sout = out + (size_t)brow0 * 256;               // t=0 out slab

  // ---- prefetch t=0 gx into registers ----
  uint2 g1[4], g2[2];
  #pragma unroll
  for (int n = 0; n < 4; ++n) g1[n] = *(const uint2*)(gp + voff1[n]);
  #pragma unroll
  for (int n = 0; n < 2; ++n) g2[n] = *(const uint2*)(gp + voff2[n]);
  __syncthreads();   // h_s/hA visible

  for (int t = 0; t < 511; ++t) {
    gp += TSTEP;                     // uniform SGPR induction -> tile t+1

    // ---------- phase 1: z,r ----------
    const int cb1 = wid * 64;        // gate col base (z: 0..255, r: 256..511)
    f32x4 acc[4];
    #pragma unroll
    for (int n = 0; n < 4; ++n) acc[n] = unpk(g1[n]);
    #pragma unroll
    for (int n = 0; n < 4; ++n) g1[n] = *(const uint2*)(gp + voff1[n]);

    #pragma unroll
    for (int kk = 0; kk < 8; ++kk) {   // compile-time kk (rule #20)
      bf16x8 hf = *(const bf16x8*)&hA[kk * 512 + lane * 8];   // linear, 0-conflict
      #pragma unroll
      for (int n = 0; n < 4; ++n)      // SWAPPED: weights as A, h^T as B
        acc[n] = __builtin_amdgcn_mfma_f32_16x16x32_bf16(w1[n][kk], hf, acc[n], 0, 0, 0);
    }
    if (wid < 4) {         // z gate
      #pragma unroll
      for (int n = 0; n < 4; ++n) {
        const int c0 = cb1 + n * 16 + lg * 4;
        f32x4 zv;
        #pragma unroll
        for (int r = 0; r < 4; ++r) zv[r] = sigmoid_f(acc[n][r]);
        *(f32x4*)&zt_s[l15][c0] = zv;
      }
    } else {               // r gate -> rh = r*h (frag-ordered)
      #pragma unroll
      for (int n = 0; n < 4; ++n) {
        const int c0h = (cb1 - 256) + n * 16 + lg * 4;
        f32x4 hv = *(const f32x4*)&h_s[l15][c0h];
        float rh0 = sigmoid_f(acc[n][0]) * hv[0];
        float rh1 = sigmoid_f(acc[n][1]) * hv[1];
        float rh2 = sigmoid_f(acc[n][2]) * hv[2];
        float rh3 = sigmoid_f(acc[n][3]) * hv[3];
        uint2 pk; pk.x = cvt_pk_bf16(rh0, rh1); pk.y = cvt_pk_bf16(rh2, rh3);
        *(uint2*)&rhA[frag_off(c0h, l15)] = pk;
      }
    }
    asm volatile("s_waitcnt lgkmcnt(0)" ::: "memory");
    __builtin_amdgcn_s_barrier();
    __builtin_amdgcn_sched_barrier(0);

    // ---------- phase 2: cand + h update ----------
    f32x4 acc2[2];
    #pragma unroll
    for (int n = 0; n < 2; ++n) acc2[n] = unpk(g2[n]);
    #pragma unroll
    for (int n = 0; n < 2; ++n) g2[n] = *(const uint2*)(gp + voff2[n]);

    #pragma unroll
    for (int kk = 0; kk < 8; ++kk) {   // compile-time kk
      bf16x8 rf = *(const bf16x8*)&rhA[kk * 512 + lane * 8];  // linear, 0-conflict
      #pragma unroll
      for (int n = 0; n < 2; ++n)
        acc2[n] = __builtin_amdgcn_mfma_f32_16x16x32_bf16(w2[n][kk], rf, acc2[n], 0, 0, 0);
    }
    #pragma unroll
    for (int n = 0; n < 2; ++n) {
      const int j0 = wid * 32 + n * 16 + lg * 4;
      f32x4 zv = *(const f32x4*)&zt_s[l15][j0];
      f32x4 hp = *(const f32x4*)&h_s[l15][j0];
      f32x4 ht;
      #pragma unroll
      for (int r = 0; r < 4; ++r) {
        float th = tanh_f(acc2[n][r]);
        ht[r] = hp[r] + zv[r] * (th - hp[r]);
      }
      *(f32x4*)(sout + ooff[n]) = ht;
      *(f32x4*)&h_s[l15][j0] = ht;
      uint2 pk; pk.x = cvt_pk_bf16(ht[0], ht[1]); pk.y = cvt_pk_bf16(ht[2], ht[3]);
      *(uint2*)&hA[frag_off(j0, l15)] = pk;
    }
    sout += 65536;                     // uniform induction
    asm volatile("s_waitcnt lgkmcnt(0)" ::: "memory");
    __builtin_amdgcn_s_barrier();
    __builtin_amdgcn_sched_barrier(0);
  }

  // ---------- peeled final step t=511 (no prefetch) ----------
  {
    const int cb1 = wid * 64;
    f32x4 acc[4];
    #pragma unroll
    for (int n = 0; n < 4; ++n) acc[n] = unpk(g1[n]);
    #pragma unroll
    for (int kk = 0; kk < 8; ++kk) {
      bf16x8 hf = *(const bf16x8*)&hA[kk * 512 + lane * 8];
      #pragma unroll
      for (int n = 0; n < 4; ++n)
        acc[n] = __builtin_amdgcn_mfma_f32_16x16x32_bf16(w1[n][kk], hf, acc[n], 0, 0, 0);
    }
    if (wid < 4) {
      #pragma unroll
      for (int n = 0; n < 4; ++n) {
        const int c0 = cb1 + n * 16 + lg * 4;
        f32x4 zv;
        #pragma unroll
        for (int r = 0; r < 4; ++r) zv[r] = sigmoid_f(acc[n][r]);
        *(f32x4*)&zt_s[l15][c0] = zv;
      }
    } else {
      #pragma unroll
      for (int n = 0; n < 4; ++n) {
        const int c0h = (cb1 - 256) + n * 16 + lg * 4;
        f32x4 hv = *(const f32x4*)&h_s[l15][c0h];
        float rh0 = sigmoid_f(acc[n][0]) * hv[0];
        float rh1 = sigmoid_f(acc[n][1]) * hv[1];
        float rh2 = sigmoid_f(acc[n][2]) * hv[2];
        float rh3 = sigmoid_f(acc[n][3]) * hv[3];
        uint2 pk; pk.x = cvt_pk_bf16(rh0, rh1); pk.y = cvt_pk_bf16(rh2, rh3);
        *(uint2*)&rhA[frag_off(c0h, l15)] = pk;
      }
    }
    asm volatile("s_waitcnt lgkmcnt(0)" ::: "memory");
    __builtin_amdgcn_s_barrier();
    __builtin_amdgcn_sched_barrier(0);

    f32x4 acc2[2];
    #pragma unroll
    for (int n = 0; n < 2; ++n) acc2[n] = unpk(g2[n]);
    #pragma unroll
    for (int kk = 0; kk < 8; ++kk) {
      bf16x8 rf = *(const bf16x8*)&rhA[kk * 512 + lane * 8];
      #pragma unroll
      for (int n = 0; n < 2; ++n)
        acc2[n] = __builtin_amdgcn_mfma_f32_16x16x32_bf16(w2[n][kk], rf, acc2[n], 0, 0, 0);
    }
    #pragma unroll
    for (int n = 0; n < 2; ++n) {
      f32x4 zv = *(const f32x4*)&zt_s[l15][wid * 32 + n * 16 + lg * 4];
      f32x4 hp = *(const f32x4*)&h_s[l15][wid * 32 + n * 16 + lg * 4];
      f32x4 ht;
      #pragma unroll
      for (int r = 0; r < 4; ++r) {
        float th = tanh_f(acc2[n][r]);
        ht[r] = hp[r] + zv[r] * (th - hp[r]);
      }
      *(f32x4*)(sout + ooff[n]) = ht;                          // hAll[511]
      *(f32x4*)(out + 33554432 + (size_t)brow0 * 256 + ooff[n]) = ht;  // h_final
    }
  }
}

extern "C" void kernel_launch(void* const* d_in, const int* in_sizes, int n_in,
                              void* d_out, int out_size, void* d_ws, size_t ws_size,
                              hipStream_t stream) {
  const float* x  = (const float*)d_in[0];
  const float* h0 = (const float*)d_in[1];
  const float* Wz = (const float*)d_in[2];
  const float* bz = (const float*)d_in[3];
  const float* Wr = (const float*)d_in[4];
  const float* br = (const float*)d_in[5];
  const float* Wc = (const float*)d_in[6];
  const float* bc = (const float*)d_in[7];
  float* out = (float*)d_out;
  unsigned short* gxbuf = (unsigned short*)d_ws;   // 768*131072*2 = 201.3 MB

  dim3 gridA(2048, 12);
  gru_gx_kernel<<<gridA, 256, 0, stream>>>(x, Wz, Wr, Wc, bz, br, bc, gxbuf);
  gru_rec_kernel<<<16, 512, 0, stream>>>(gxbuf, h0, Wz, Wr, Wc, out);
}

// Round 13
// 1145.641 us; speedup vs baseline: 1.2640x; 1.1455x over previous
//
#include <hip/hip_runtime.h>

// GRU: T=512, B=256, I=H=256, fp32 in/out.
// Stage A (parallel GEMM): Gx = x @ Wx_cat^T + b, bf16 in d_ws.
//   Layout: gx[tile = t*16+bg][colblk 0..191][batch 0..15][colin 0..3], bf16.
// Stage B (recurrent): 16 WGs x 512 thr (8 waves); 16 batch rows/WG.
// r13: COLUMN-BLOCK OWNERSHIP — wave w owns cols [32w,32w+32) for z, r, AND
//   cand. z and h live entirely in REGISTERS (no zt_s/h_s LDS): phase 1 runs
//   two independent MFMA chains (z,r) off hA, keeps z in regs, writes only
//   rh (bf16 frags) to LDS; phase 2 does cand MFMA off rhA, tanh, register
//   h-update, out store, hA pack. Only hA+rhA (16KB) remain in LDS.
//   Weights: wz/wr/wc[2][8] = 192 regs (same budget as r10).
// Retained from r10: direct-reg gx prefetch 1 step ahead, raw lgkmcnt-only
//   barriers, frag-ordered hA/rhA (0-conflict ds_read_b128).
// Rule #20: all register arrays indexed by compile-time constants only.

typedef float f32x4 __attribute__((ext_vector_type(4)));
typedef short bf16x8 __attribute__((ext_vector_type(8)));

__device__ __forceinline__ unsigned short f2bf(float f) {
  union { float f; unsigned int u; } v; v.f = f;
  unsigned int u = v.u + 0x7fffu + ((v.u >> 16) & 1u);   // RNE
  return (unsigned short)(u >> 16);
}
__device__ __forceinline__ float u2f(unsigned int u) {
  union { unsigned int u; float f; } v; v.u = u; return v.f;
}
__device__ __forceinline__ unsigned int cvt_pk_bf16(float lo, float hi) {
  unsigned int r;
  asm("v_cvt_pk_bf16_f32 %0, %1, %2" : "=v"(r) : "v"(lo), "v"(hi));
  return r;
}
__device__ __forceinline__ float sigmoid_f(float x) {
  return __builtin_amdgcn_rcpf(1.f + __expf(-x));
}
__device__ __forceinline__ float tanh_f(float x) {
  float e = __expf(2.f * x);
  return 1.f - 2.f * __builtin_amdgcn_rcpf(e + 1.f);
}
__device__ __forceinline__ f32x4 unpk(uint2 gv) {
  f32x4 a;
  a[0] = u2f(gv.x << 16); a[1] = u2f(gv.x & 0xffff0000u);
  a[2] = u2f(gv.y << 16); a[3] = u2f(gv.y & 0xffff0000u);
  return a;
}
// col j (0..255), batch b -> short offset in fragment-ordered [kk][lg][16][8]
__device__ __forceinline__ int frag_off(int j, int b) {
  return ((j >> 5) * 64 + ((j >> 3) & 3) * 16 + b) * 8 + (j & 7);
}

// ---------------- Stage A ----------------
// grid (2048, 12), block 256 (4 waves). Tile 64M x 64N, K=256 in 4 chunks.
__global__ __launch_bounds__(256) void gru_gx_kernel(
    const float* __restrict__ x,
    const float* __restrict__ Wz, const float* __restrict__ Wr, const float* __restrict__ Wc,
    const float* __restrict__ bz, const float* __restrict__ br, const float* __restrict__ bc,
    unsigned short* __restrict__ gx)
{
  __shared__ __align__(16) unsigned short As[64][72];  // [m][k] bf16, +8 pad
  __shared__ __align__(16) unsigned short Bs[64][72];  // [j][k] bf16

  const int tid  = threadIdx.x;
  const int lane = tid & 63;
  const int wid  = tid >> 6;       // 0..3
  const int l15  = lane & 15;
  const int lg   = lane >> 4;      // 0..3
  const int m0   = blockIdx.x * 64;      // m = t*256 + b
  const int by   = blockIdx.y;           // 0..11
  const int gate = by >> 2;
  const int jb   = (by & 3) * 64;
  const float* W    = (gate == 0) ? Wz : ((gate == 1) ? Wr : Wc);
  const float* bias = (gate == 0) ? bz : ((gate == 1) ? br : bc);

  f32x4 acc[4];
  #pragma unroll
  for (int n = 0; n < 4; ++n) acc[n] = (f32x4){0.f, 0.f, 0.f, 0.f};

  for (int k0 = 0; k0 < 256; k0 += 64) {
    #pragma unroll
    for (int i = 0; i < 4; ++i) {
      int idx = tid + i * 256;              // 0..1023
      int row = idx >> 4;                   // 0..63
      int kq  = (idx & 15) << 2;            // 0..60 step 4
      float4 va = *(const float4*)(x + (size_t)(m0 + row) * 256 + k0 + kq);
      ushort4 ua; ua.x = f2bf(va.x); ua.y = f2bf(va.y); ua.z = f2bf(va.z); ua.w = f2bf(va.w);
      *(ushort4*)&As[row][kq] = ua;
      float4 vb = *(const float4*)(W + (size_t)(jb + row) * 512 + 256 + k0 + kq);
      ushort4 ub; ub.x = f2bf(vb.x); ub.y = f2bf(vb.y); ub.z = f2bf(vb.z); ub.w = f2bf(vb.w);
      *(ushort4*)&Bs[row][kq] = ub;
    }
    __syncthreads();
    #pragma unroll
    for (int ks = 0; ks < 64; ks += 32) {
      bf16x8 af = *(const bf16x8*)&As[wid * 16 + l15][ks + lg * 8];
      #pragma unroll
      for (int n = 0; n < 4; ++n) {
        bf16x8 bf = *(const bf16x8*)&Bs[n * 16 + l15][ks + lg * 8];
        acc[n] = __builtin_amdgcn_mfma_f32_16x16x32_bf16(af, bf, acc[n], 0, 0, 0);
      }
    }
    __syncthreads();
  }

  // bias + bf16; transpose staging: Ts[m 64][j 64] (reuse As, stride 72)
  #pragma unroll
  for (int n = 0; n < 4; ++n) {
    float bv = bias[jb + n * 16 + l15];
    #pragma unroll
    for (int r = 0; r < 4; ++r) {
      As[wid * 16 + lg * 4 + r][n * 16 + l15] = f2bf(acc[n][r] + bv);
    }
  }
  __syncthreads();

  const int tt    = m0 >> 8;       // t (tile spans a single t since 64 | 256)
  const int b0    = m0 & 255;      // batch base, 64-aligned
  const int jbase = by * 64;       // global output col base
  #pragma unroll
  for (int i = 0; i < 2; ++i) {
    int u    = tid + i * 256;      // 0..511
    int bg_l = u >> 7;             // 0..3 (16-batch group within tile's 64 batches)
    int rem  = u & 127;
    int cb_l = rem >> 3;           // 0..15 colblk within the 64-col slice
    int bp   = rem & 7;            // batch pair
    int row0 = bg_l * 16 + bp * 2;
    uint2 lo = *(const uint2*)&As[row0][cb_l * 4];
    uint2 hi = *(const uint2*)&As[row0 + 1][cb_l * 4];
    uint4 val; val.x = lo.x; val.y = lo.y; val.z = hi.x; val.w = hi.y;
    size_t off = (((size_t)tt * 16 + (b0 >> 4) + bg_l) * 192 + (jbase >> 2) + cb_l) * 64
                 + (size_t)bp * 8;   // shorts
    *(uint4*)(gx + off) = val;
  }
}

// ---------------- Stage B ----------------
// grid 16, block 512 (8 waves). WG wg owns batch rows [16wg, 16wg+16).
// Wave w owns output cols [32w, 32w+32) for z, r, and cand.
__global__ __launch_bounds__(512, 1) void gru_rec_kernel(
    const unsigned short* __restrict__ gx,
    const float* __restrict__ h0,
    const float* __restrict__ Wz, const float* __restrict__ Wr, const float* __restrict__ Wc,
    float* __restrict__ out)
{
  __shared__ __align__(16) unsigned short hA[4096];      // bf16 h, frag-ordered
  __shared__ __align__(16) unsigned short rhA[4096];     // bf16 r*h, frag-ordered

  const int tid   = threadIdx.x;
  const int lane  = tid & 63;
  const int wid   = tid >> 6;       // 0..7
  const int l15   = lane & 15;
  const int lg    = lane >> 4;      // 0..3
  const int wg    = blockIdx.x;
  const int brow0 = wg * 16;
  const int cb    = wid * 32;       // owned col block

  // ---- persistent weights: bf16 MFMA A-fragments, 3 x 64 = 192 regs ----
  bf16x8 wz[2][8], wr[2][8], wc[2][8];
  #pragma unroll
  for (int n = 0; n < 2; ++n) {
    const int j = cb + n * 16 + l15;
    #pragma unroll
    for (int kk = 0; kk < 8; ++kk) {
      const int k = kk * 32 + lg * 8;
      #pragma unroll
      for (int g = 0; g < 3; ++g) {
        const float* W = (g == 0) ? Wz : ((g == 1) ? Wr : Wc);
        const float* p = W + (size_t)j * 512 + k;      // h-part: cols [0,256)
        float4 a = *(const float4*)p;
        float4 b = *(const float4*)(p + 4);
        bf16x8 f;
        f[0] = (short)f2bf(a.x); f[1] = (short)f2bf(a.y);
        f[2] = (short)f2bf(a.z); f[3] = (short)f2bf(a.w);
        f[4] = (short)f2bf(b.x); f[5] = (short)f2bf(b.y);
        f[6] = (short)f2bf(b.z); f[7] = (short)f2bf(b.w);
        if (g == 0) wz[n][kk] = f; else if (g == 1) wr[n][kk] = f; else wc[n][kk] = f;
      }
    }
  }

  // ---- init h: registers (owned cols) + hA (all cols, bf16 frags) ----
  f32x4 hreg[2];
  #pragma unroll
  for (int n = 0; n < 2; ++n)
    hreg[n] = *(const f32x4*)(h0 + (size_t)(brow0 + l15) * 256 + cb + n * 16 + lg * 4);
  for (int idx = tid; idx < 16 * 256; idx += 512) {
    int r = idx >> 8, c = idx & 255;
    hA[frag_off(c, r)] = f2bf(h0[(size_t)(brow0 + r) * 256 + c]);
  }

  // ---- prefetch t=0 gx into registers (6 x uint2) ----
  uint2 g1z[2], g1r[2], g2[2];
  {
    const size_t tb = (size_t)wg * 12288;
    #pragma unroll
    for (int n = 0; n < 2; ++n) {
      g1z[n] = *(const uint2*)(gx + tb + (size_t)(wid * 8 + n * 4 + lg) * 64 + l15 * 4);
      g1r[n] = *(const uint2*)(gx + tb + (size_t)(64 + wid * 8 + n * 4 + lg) * 64 + l15 * 4);
      g2[n]  = *(const uint2*)(gx + tb + (size_t)(128 + wid * 8 + n * 4 + lg) * 64 + l15 * 4);
    }
  }
  __syncthreads();   // hA visible

  for (int t = 0; t < 512; ++t) {
    const int tn = (t < 511) ? (t + 1) : 511;
    const size_t tbn = ((size_t)tn * 16 + wg) * 12288;

    // ---------- phase 1: z and r (two independent MFMA chains) ----------
    f32x4 accZ[2], accR[2];
    #pragma unroll
    for (int n = 0; n < 2; ++n) { accZ[n] = unpk(g1z[n]); accR[n] = unpk(g1r[n]); }
    // issue next-step prefetch (full step to land)
    #pragma unroll
    for (int n = 0; n < 2; ++n) {
      g1z[n] = *(const uint2*)(gx + tbn + (size_t)(wid * 8 + n * 4 + lg) * 64 + l15 * 4);
      g1r[n] = *(const uint2*)(gx + tbn + (size_t)(64 + wid * 8 + n * 4 + lg) * 64 + l15 * 4);
    }

    #pragma unroll
    for (int kk = 0; kk < 8; ++kk) {   // compile-time kk (rule #20)
      bf16x8 hf = *(const bf16x8*)&hA[kk * 512 + lane * 8];   // linear, 0-conflict
      accZ[0] = __builtin_amdgcn_mfma_f32_16x16x32_bf16(wz[0][kk], hf, accZ[0], 0, 0, 0);
      accZ[1] = __builtin_amdgcn_mfma_f32_16x16x32_bf16(wz[1][kk], hf, accZ[1], 0, 0, 0);
      accR[0] = __builtin_amdgcn_mfma_f32_16x16x32_bf16(wr[0][kk], hf, accR[0], 0, 0, 0);
      accR[1] = __builtin_amdgcn_mfma_f32_16x16x32_bf16(wr[1][kk], hf, accR[1], 0, 0, 0);
    }
    f32x4 zreg[2];
    #pragma unroll
    for (int n = 0; n < 2; ++n) {
      #pragma unroll
      for (int r = 0; r < 4; ++r) zreg[n][r] = sigmoid_f(accZ[n][r]);
      float rh0 = sigmoid_f(accR[n][0]) * hreg[n][0];
      float rh1 = sigmoid_f(accR[n][1]) * hreg[n][1];
      float rh2 = sigmoid_f(accR[n][2]) * hreg[n][2];
      float rh3 = sigmoid_f(accR[n][3]) * hreg[n][3];
      uint2 pk; pk.x = cvt_pk_bf16(rh0, rh1); pk.y = cvt_pk_bf16(rh2, rh3);
      *(uint2*)&rhA[frag_off(cb + n * 16 + lg * 4, l15)] = pk;
    }
    // raw barrier: LDS ordering only, never drain vmcnt in the loop
    asm volatile("s_waitcnt lgkmcnt(0)" ::: "memory");
    __builtin_amdgcn_s_barrier();
    __builtin_amdgcn_sched_barrier(0);

    // ---------- phase 2: cand + register h update ----------
    f32x4 acc2[2];
    #pragma unroll
    for (int n = 0; n < 2; ++n) acc2[n] = unpk(g2[n]);
    #pragma unroll
    for (int n = 0; n < 2; ++n)
      g2[n] = *(const uint2*)(gx + tbn + (size_t)(128 + wid * 8 + n * 4 + lg) * 64 + l15 * 4);

    #pragma unroll
    for (int kk = 0; kk < 8; ++kk) {   // compile-time kk
      bf16x8 rf = *(const bf16x8*)&rhA[kk * 512 + lane * 8];  // linear, 0-conflict
      acc2[0] = __builtin_amdgcn_mfma_f32_16x16x32_bf16(wc[0][kk], rf, acc2[0], 0, 0, 0);
      acc2[1] = __builtin_amdgcn_mfma_f32_16x16x32_bf16(wc[1][kk], rf, acc2[1], 0, 0, 0);
    }
    #pragma unroll
    for (int n = 0; n < 2; ++n) {
      #pragma unroll
      for (int r = 0; r < 4; ++r) {
        float th = tanh_f(acc2[n][r]);
        hreg[n][r] = hreg[n][r] + zreg[n][r] * (th - hreg[n][r]);
      }
      *(f32x4*)(out + (size_t)t * 65536 + (size_t)(brow0 + l15) * 256 + cb + n * 16 + lg * 4) = hreg[n];
      if (t == 511)
        *(f32x4*)(out + (size_t)33554432 + (size_t)(brow0 + l15) * 256 + cb + n * 16 + lg * 4) = hreg[n];
      uint2 pk; pk.x = cvt_pk_bf16(hreg[n][0], hreg[n][1]);
      pk.y = cvt_pk_bf16(hreg[n][2], hreg[n][3]);
      *(uint2*)&hA[frag_off(cb + n * 16 + lg * 4, l15)] = pk;
    }
    asm volatile("s_waitcnt lgkmcnt(0)" ::: "memory");
    __builtin_amdgcn_s_barrier();
    __builtin_amdgcn_sched_barrier(0);
  }
}

extern "C" void kernel_launch(void* const* d_in, const int* in_sizes, int n_in,
                              void* d_out, int out_size, void* d_ws, size_t ws_size,
                              hipStream_t stream) {
  const float* x  = (const float*)d_in[0];
  const float* h0 = (const float*)d_in[1];
  const float* Wz = (const float*)d_in[2];
  const float* bz = (const float*)d_in[3];
  const float* Wr = (const float*)d_in[4];
  const float* br = (const float*)d_in[5];
  const float* Wc = (const float*)d_in[6];
  const float* bc = (const float*)d_in[7];
  float* out = (float*)d_out;
  unsigned short* gxbuf = (unsigned short*)d_ws;   // 768*131072*2 = 201.3 MB

  dim3 gridA(2048, 12);
  gru_gx_kernel<<<gridA, 256, 0, stream>>>(x, Wz, Wr, Wc, bz, br, bc, gxbuf);
  gru_rec_kernel<<<16, 512, 0, stream>>>(gxbuf, h0, Wz, Wr, Wc, out);
}

// Round 15
// 1041.675 us; speedup vs baseline: 1.3902x; 1.0998x over previous
//
#include <hip/hip_runtime.h>

// GRU: T=512, B=256, I=H=256, fp32 in/out.
// Stage A (parallel GEMM, r15): grid (2048,3) — one GATE per blockIdx.y,
//   tile 64M x 256N, K=256 in 4 chunks. x staged ONCE per chunk (was 12x
//   total across y-blocks). f32->bf16 via v_cvt_pk_bf16_f32. Bias folded
//   (NO scaling — r14's log2e+asm-exp2 bundle NaN'd; decomposing).
//   Layout: gx[tile = t*16+bg][colblk 0..191][batch 0..15][colin 0..3], bf16.
// Stage B (recurrent) = r13 VERBATIM (proven 900us): 16 WGs x 512 thr;
//   wave w owns cols [32w,32w+32) for z,r,cand; z,h in registers; weights
//   persistent (192 regs); frag-ordered hA/rhA; direct-reg gx prefetch;
//   raw lgkmcnt-only barriers.
// Rule #20: all register arrays indexed by compile-time constants only.

typedef float f32x4 __attribute__((ext_vector_type(4)));
typedef short bf16x8 __attribute__((ext_vector_type(8)));

__device__ __forceinline__ unsigned short f2bf(float f) {
  union { float f; unsigned int u; } v; v.f = f;
  unsigned int u = v.u + 0x7fffu + ((v.u >> 16) & 1u);   // RNE
  return (unsigned short)(u >> 16);
}
__device__ __forceinline__ float u2f(unsigned int u) {
  union { unsigned int u; float f; } v; v.u = u; return v.f;
}
__device__ __forceinline__ unsigned int cvt_pk_bf16(float lo, float hi) {
  unsigned int r;
  asm("v_cvt_pk_bf16_f32 %0, %1, %2" : "=v"(r) : "v"(lo), "v"(hi));
  return r;
}
__device__ __forceinline__ float sigmoid_f(float x) {
  return __builtin_amdgcn_rcpf(1.f + __expf(-x));
}
__device__ __forceinline__ float tanh_f(float x) {
  float e = __expf(2.f * x);
  return 1.f - 2.f * __builtin_amdgcn_rcpf(e + 1.f);
}
__device__ __forceinline__ f32x4 unpk(uint2 gv) {
  f32x4 a;
  a[0] = u2f(gv.x << 16); a[1] = u2f(gv.x & 0xffff0000u);
  a[2] = u2f(gv.y << 16); a[3] = u2f(gv.y & 0xffff0000u);
  return a;
}
// col j (0..255), batch b -> short offset in fragment-ordered [kk][lg][16][8]
__device__ __forceinline__ int frag_off(int j, int b) {
  return ((j >> 5) * 64 + ((j >> 3) & 3) * 16 + b) * 8 + (j & 7);
}

// ---------------- Stage A ----------------
// grid (2048, 3), block 256 (4 waves). Tile 64M x 256N (one gate), K=256.
__global__ __launch_bounds__(256) void gru_gx_kernel(
    const float* __restrict__ x,
    const float* __restrict__ Wz, const float* __restrict__ Wr, const float* __restrict__ Wc,
    const float* __restrict__ bz, const float* __restrict__ br, const float* __restrict__ bc,
    unsigned short* __restrict__ gx)
{
  __shared__ __align__(16) unsigned short As[64][72];    // x tile [m][k], +8 pad
  __shared__ __align__(16) unsigned short Bs[256][72];   // W tile [j][k], 36KB

  const int tid  = threadIdx.x;
  const int lane = tid & 63;
  const int wid  = tid >> 6;       // 0..3
  const int l15  = lane & 15;
  const int lg   = lane >> 4;      // 0..3
  const int m0   = blockIdx.x * 64;      // m = t*256 + b
  const int gate = blockIdx.y;           // 0=z 1=r 2=cand
  const float* W    = (gate == 0) ? Wz : ((gate == 1) ? Wr : Wc);
  const float* bias = (gate == 0) ? bz : ((gate == 1) ? br : bc);

  f32x4 acc[16];
  #pragma unroll
  for (int n = 0; n < 16; ++n) acc[n] = (f32x4){0.f, 0.f, 0.f, 0.f};

  for (int k0 = 0; k0 < 256; k0 += 64) {
    #pragma unroll
    for (int i = 0; i < 4; ++i) {            // x: 64x64
      int idx = tid + i * 256;               // 0..1023
      int row = idx >> 4;
      int kq  = (idx & 15) << 2;
      float4 v = *(const float4*)(x + (size_t)(m0 + row) * 256 + k0 + kq);
      uint2 p; p.x = cvt_pk_bf16(v.x, v.y); p.y = cvt_pk_bf16(v.z, v.w);
      *(uint2*)&As[row][kq] = p;
    }
    #pragma unroll
    for (int i = 0; i < 16; ++i) {           // W: 256x64 (x-part cols 256+k)
      int idx = tid + i * 256;               // 0..4095
      int row = idx >> 4;
      int kq  = (idx & 15) << 2;
      float4 v = *(const float4*)(W + (size_t)row * 512 + 256 + k0 + kq);
      uint2 p; p.x = cvt_pk_bf16(v.x, v.y); p.y = cvt_pk_bf16(v.z, v.w);
      *(uint2*)&Bs[row][kq] = p;
    }
    __syncthreads();
    #pragma unroll
    for (int ks = 0; ks < 64; ks += 32) {
      bf16x8 af = *(const bf16x8*)&As[wid * 16 + l15][ks + lg * 8];
      #pragma unroll
      for (int n = 0; n < 16; ++n) {
        bf16x8 bf = *(const bf16x8*)&Bs[n * 16 + l15][ks + lg * 8];
        acc[n] = __builtin_amdgcn_mfma_f32_16x16x32_bf16(af, bf, acc[n], 0, 0, 0);
      }
    }
    __syncthreads();
  }

  // epilogue: acc + bias -> bf16, stage as Ts[m 64][j 256] (reuse Bs)
  unsigned short* Ts = &Bs[0][0];            // stride 268 shorts (8B-aligned rows)
  const int TS = 268;
  #pragma unroll
  for (int n = 0; n < 16; ++n) {
    const int j = n * 16 + l15;
    float bv = bias[j];
    #pragma unroll
    for (int r = 0; r < 4; ++r) {
      unsigned int pk = cvt_pk_bf16(acc[n][r] + bv, 0.f);
      Ts[(wid * 16 + lg * 4 + r) * TS + j] = (unsigned short)pk;
    }
  }
  __syncthreads();

  const int tt  = m0 >> 8;        // t (tile spans one t since 64 | 256)
  const int bg0 = (m0 & 255) >> 4;
  #pragma unroll
  for (int i = 0; i < 8; ++i) {
    int idx  = tid + i * 256;     // 0..2047
    int bg_l = idx >> 9;          // 0..3
    int rem  = idx & 511;
    int cb_l = rem >> 3;          // 0..63 (colblk within gate)
    int bp   = rem & 7;           // batch pair
    int m    = bg_l * 16 + bp * 2;
    uint2 lo = *(const uint2*)&Ts[(size_t)m * TS + cb_l * 4];
    uint2 hi = *(const uint2*)&Ts[(size_t)(m + 1) * TS + cb_l * 4];
    uint4 val; val.x = lo.x; val.y = lo.y; val.z = hi.x; val.w = hi.y;
    size_t off = (((size_t)tt * 16 + bg0 + bg_l) * 192 + gate * 64 + cb_l) * 64
                 + (size_t)bp * 8;   // shorts
    *(uint4*)(gx + off) = val;
  }
}

// ---------------- Stage B ---------------- (r13 verbatim)
// grid 16, block 512 (8 waves). WG wg owns batch rows [16wg, 16wg+16).
// Wave w owns output cols [32w, 32w+32) for z, r, and cand.
__global__ __launch_bounds__(512, 1) void gru_rec_kernel(
    const unsigned short* __restrict__ gx,
    const float* __restrict__ h0,
    const float* __restrict__ Wz, const float* __restrict__ Wr, const float* __restrict__ Wc,
    float* __restrict__ out)
{
  __shared__ __align__(16) unsigned short hA[4096];      // bf16 h, frag-ordered
  __shared__ __align__(16) unsigned short rhA[4096];     // bf16 r*h, frag-ordered

  const int tid   = threadIdx.x;
  const int lane  = tid & 63;
  const int wid   = tid >> 6;       // 0..7
  const int l15   = lane & 15;
  const int lg    = lane >> 4;      // 0..3
  const int wg    = blockIdx.x;
  const int brow0 = wg * 16;
  const int cb    = wid * 32;       // owned col block

  // ---- persistent weights: bf16 MFMA A-fragments, 3 x 64 = 192 regs ----
  bf16x8 wz[2][8], wr[2][8], wc[2][8];
  #pragma unroll
  for (int n = 0; n < 2; ++n) {
    const int j = cb + n * 16 + l15;
    #pragma unroll
    for (int kk = 0; kk < 8; ++kk) {
      const int k = kk * 32 + lg * 8;
      #pragma unroll
      for (int g = 0; g < 3; ++g) {
        const float* W = (g == 0) ? Wz : ((g == 1) ? Wr : Wc);
        const float* p = W + (size_t)j * 512 + k;      // h-part: cols [0,256)
        float4 a = *(const float4*)p;
        float4 b = *(const float4*)(p + 4);
        bf16x8 f;
        f[0] = (short)f2bf(a.x); f[1] = (short)f2bf(a.y);
        f[2] = (short)f2bf(a.z); f[3] = (short)f2bf(a.w);
        f[4] = (short)f2bf(b.x); f[5] = (short)f2bf(b.y);
        f[6] = (short)f2bf(b.z); f[7] = (short)f2bf(b.w);
        if (g == 0) wz[n][kk] = f; else if (g == 1) wr[n][kk] = f; else wc[n][kk] = f;
      }
    }
  }

  // ---- init h: registers (owned cols) + hA (all cols, bf16 frags) ----
  f32x4 hreg[2];
  #pragma unroll
  for (int n = 0; n < 2; ++n)
    hreg[n] = *(const f32x4*)(h0 + (size_t)(brow0 + l15) * 256 + cb + n * 16 + lg * 4);
  for (int idx = tid; idx < 16 * 256; idx += 512) {
    int r = idx >> 8, c = idx & 255;
    hA[frag_off(c, r)] = f2bf(h0[(size_t)(brow0 + r) * 256 + c]);
  }

  // ---- prefetch t=0 gx into registers (6 x uint2) ----
  uint2 g1z[2], g1r[2], g2[2];
  {
    const size_t tb = (size_t)wg * 12288;
    #pragma unroll
    for (int n = 0; n < 2; ++n) {
      g1z[n] = *(const uint2*)(gx + tb + (size_t)(wid * 8 + n * 4 + lg) * 64 + l15 * 4);
      g1r[n] = *(const uint2*)(gx + tb + (size_t)(64 + wid * 8 + n * 4 + lg) * 64 + l15 * 4);
      g2[n]  = *(const uint2*)(gx + tb + (size_t)(128 + wid * 8 + n * 4 + lg) * 64 + l15 * 4);
    }
  }
  __syncthreads();   // hA visible

  for (int t = 0; t < 512; ++t) {
    const int tn = (t < 511) ? (t + 1) : 511;
    const size_t tbn = ((size_t)tn * 16 + wg) * 12288;

    // ---------- phase 1: z and r (two independent MFMA chains) ----------
    f32x4 accZ[2], accR[2];
    #pragma unroll
    for (int n = 0; n < 2; ++n) { accZ[n] = unpk(g1z[n]); accR[n] = unpk(g1r[n]); }
    // issue next-step prefetch (full step to land)
    #pragma unroll
    for (int n = 0; n < 2; ++n) {
      g1z[n] = *(const uint2*)(gx + tbn + (size_t)(wid * 8 + n * 4 + lg) * 64 + l15 * 4);
      g1r[n] = *(const uint2*)(gx + tbn + (size_t)(64 + wid * 8 + n * 4 + lg) * 64 + l15 * 4);
    }

    #pragma unroll
    for (int kk = 0; kk < 8; ++kk) {   // compile-time kk (rule #20)
      bf16x8 hf = *(const bf16x8*)&hA[kk * 512 + lane * 8];   // linear, 0-conflict
      accZ[0] = __builtin_amdgcn_mfma_f32_16x16x32_bf16(wz[0][kk], hf, accZ[0], 0, 0, 0);
      accZ[1] = __builtin_amdgcn_mfma_f32_16x16x32_bf16(wz[1][kk], hf, accZ[1], 0, 0, 0);
      accR[0] = __builtin_amdgcn_mfma_f32_16x16x32_bf16(wr[0][kk], hf, accR[0], 0, 0, 0);
      accR[1] = __builtin_amdgcn_mfma_f32_16x16x32_bf16(wr[1][kk], hf, accR[1], 0, 0, 0);
    }
    f32x4 zreg[2];
    #pragma unroll
    for (int n = 0; n < 2; ++n) {
      #pragma unroll
      for (int r = 0; r < 4; ++r) zreg[n][r] = sigmoid_f(accZ[n][r]);
      float rh0 = sigmoid_f(accR[n][0]) * hreg[n][0];
      float rh1 = sigmoid_f(accR[n][1]) * hreg[n][1];
      float rh2 = sigmoid_f(accR[n][2]) * hreg[n][2];
      float rh3 = sigmoid_f(accR[n][3]) * hreg[n][3];
      uint2 pk; pk.x = cvt_pk_bf16(rh0, rh1); pk.y = cvt_pk_bf16(rh2, rh3);
      *(uint2*)&rhA[frag_off(cb + n * 16 + lg * 4, l15)] = pk;
    }
    // raw barrier: LDS ordering only, never drain vmcnt in the loop
    asm volatile("s_waitcnt lgkmcnt(0)" ::: "memory");
    __builtin_amdgcn_s_barrier();
    __builtin_amdgcn_sched_barrier(0);

    // ---------- phase 2: cand + register h update ----------
    f32x4 acc2[2];
    #pragma unroll
    for (int n = 0; n < 2; ++n) acc2[n] = unpk(g2[n]);
    #pragma unroll
    for (int n = 0; n < 2; ++n)
      g2[n] = *(const uint2*)(gx + tbn + (size_t)(128 + wid * 8 + n * 4 + lg) * 64 + l15 * 4);

    #pragma unroll
    for (int kk = 0; kk < 8; ++kk) {   // compile-time kk
      bf16x8 rf = *(const bf16x8*)&rhA[kk * 512 + lane * 8];  // linear, 0-conflict
      acc2[0] = __builtin_amdgcn_mfma_f32_16x16x32_bf16(wc[0][kk], rf, acc2[0], 0, 0, 0);
      acc2[1] = __builtin_amdgcn_mfma_f32_16x16x32_bf16(wc[1][kk], rf, acc2[1], 0, 0, 0);
    }
    #pragma unroll
    for (int n = 0; n < 2; ++n) {
      #pragma unroll
      for (int r = 0; r < 4; ++r) {
        float th = tanh_f(acc2[n][r]);
        hreg[n][r] = hreg[n][r] + zreg[n][r] * (th - hreg[n][r]);
      }
      *(f32x4*)(out + (size_t)t * 65536 + (size_t)(brow0 + l15) * 256 + cb + n * 16 + lg * 4) = hreg[n];
      if (t == 511)
        *(f32x4*)(out + (size_t)33554432 + (size_t)(brow0 + l15) * 256 + cb + n * 16 + lg * 4) = hreg[n];
      uint2 pk; pk.x = cvt_pk_bf16(hreg[n][0], hreg[n][1]);
      pk.y = cvt_pk_bf16(hreg[n][2], hreg[n][3]);
      *(uint2*)&hA[frag_off(cb + n * 16 + lg * 4, l15)] = pk;
    }
    asm volatile("s_waitcnt lgkmcnt(0)" ::: "memory");
    __builtin_amdgcn_s_barrier();
    __builtin_amdgcn_sched_barrier(0);
  }
}

extern "C" void kernel_launch(void* const* d_in, const int* in_sizes, int n_in,
                              void* d_out, int out_size, void* d_ws, size_t ws_size,
                              hipStream_t stream) {
  const float* x  = (const float*)d_in[0];
  const float* h0 = (const float*)d_in[1];
  const float* Wz = (const float*)d_in[2];
  const float* bz = (const float*)d_in[3];
  const float* Wr = (const float*)d_in[4];
  const float* br = (const float*)d_in[5];
  const float* Wc = (const float*)d_in[6];
  const float* bc = (const float*)d_in[7];
  float* out = (float*)d_out;
  unsigned short* gxbuf = (unsigned short*)d_ws;   // 768*131072*2 = 201.3 MB

  dim3 gridA(2048, 3);
  gru_gx_kernel<<<gridA, 256, 0, stream>>>(x, Wz, Wr, Wc, bz, br, bc, gxbuf);
  gru_rec_kernel<<<16, 512, 0, stream>>>(gxbuf, h0, Wz, Wr, Wc, out);
}